// Round 8
// baseline (303.928 us; speedup 1.0000x reference)
//
#include <hip/hip_runtime.h>
#include <hip/hip_bf16.h>
#include <math.h>

// Problem constants
constexpr int B    = 4;
constexpr int D    = 768;
constexpr int HW   = 1024;
constexpr int M    = B * HW;        // 4096 queries
constexpr int NDB  = 20000;
constexpr int LT   = 158;           // 128-row layout tiles (20224 rows padded)
constexpr int OUTH = 512;
constexpr int OUTW = 512;

constexpr int BM     = 256;         // db rows per gemm tile (2 layout tiles)
constexpr int BN     = 128;         // queries per tile
constexpr int KSTEPS = D / 64;      // 12 64-K steps
constexpr int NSPLIT = 16;
constexpr int NT2    = 79;          // 256-row gemm tiles
constexpr int STEPB  = 128 * 64;    // 8192 B per 64-K step-block (one layout tile)

typedef int   i32x8  __attribute__((ext_vector_type(8)));
typedef float f32x16 __attribute__((ext_vector_type(16)));

__device__ __forceinline__ void insert3(float& t0, float& t1, float& t2, float d) {
    float a0 = fminf(d, t0);
    float b0 = fmaxf(d, t0);
    float a1 = fminf(b0, t1);
    float b1 = fmaxf(b0, t1);
    t0 = a0; t1 = a1;
    t2 = fminf(b1, t2);
}

__device__ __forceinline__ unsigned int pack4_fp8(float a, float b, float c, float d) {
    int v = __builtin_amdgcn_cvt_pk_fp8_f32(a, b, 0, false);
    v = __builtin_amdgcn_cvt_pk_fp8_f32(c, d, v, true);
    return (unsigned int)v;
}

__device__ __forceinline__ void gl_lds16(const unsigned char* g, unsigned char* l) {
    __builtin_amdgcn_global_load_lds(
        (const __attribute__((address_space(1))) void*)g,
        (__attribute__((address_space(3))) void*)l, 16, 0, 0);
}

// ---------------------------------------------------------------------------
// 1) Fused converts (one launch, block-uniform branch):
//    blockIdx.x <  LT : db [20000][768] fp32 -> fp8 tiled
//                       [158][12][rg 4][h2 2][kc 2][r 32][16B], + x2 partials
//    blockIdx.x >= LT : emb [4][768][1024] -> fp8 (-2*q) tiled
//                       [32][12][rg][h2][kc][r][16B], + q2 partials
__global__ __launch_bounds__(256) void convert_all(const float* __restrict__ db,
                                                   const float* __restrict__ emb,
                                                   uint4* __restrict__ dbt8,
                                                   uint4* __restrict__ qbt8,
                                                   float* __restrict__ x2p,
                                                   float* __restrict__ q2p) {
    __shared__ float panel[128][68];
    __shared__ float part[512];
    const int g = blockIdx.y;
    const int t = threadIdx.x;

    if (blockIdx.x < LT) {
        // ---------------- db path ----------------
        const int lt = blockIdx.x;
        const int n0 = lt * 128;

        #pragma unroll
        for (int pass = 0; pass < 8; ++pass) {
            int idx = pass * 256 + t;            // 0..2047
            int row = idx >> 4, c4 = idx & 15;
            int n = n0 + row;
            float4 v = make_float4(0.f, 0.f, 0.f, 0.f);
            if (n < NDB) v = *(const float4*)(db + (size_t)n * D + g * 64 + c4 * 4);
            *(float4*)&panel[row][c4 * 4] = v;
        }
        __syncthreads();
        #pragma unroll
        for (int pass = 0; pass < 2; ++pass) {
            int idx = pass * 256 + t;            // bits [rg:2][h2:1][kc:1][r:5]
            int r  = idx & 31;
            int kc = (idx >> 5) & 1;
            int h2 = (idx >> 6) & 1;
            int rg = idx >> 7;
            int row  = rg * 32 + r;
            int kloc = kc * 32 + h2 * 16;
            float4 va = *(const float4*)&panel[row][kloc + 0];
            float4 vb = *(const float4*)&panel[row][kloc + 4];
            float4 vc = *(const float4*)&panel[row][kloc + 8];
            float4 vd = *(const float4*)&panel[row][kloc + 12];
            float ss = va.x*va.x + va.y*va.y + va.z*va.z + va.w*va.w
                     + vb.x*vb.x + vb.y*vb.y + vb.z*vb.z + vb.w*vb.w
                     + vc.x*vc.x + vc.y*vc.y + vc.z*vc.z + vc.w*vc.w
                     + vd.x*vd.x + vd.y*vd.y + vd.z*vd.z + vd.w*vd.w;
            uint4 o;
            o.x = pack4_fp8(va.x, va.y, va.z, va.w);
            o.y = pack4_fp8(vb.x, vb.y, vb.z, vb.w);
            o.z = pack4_fp8(vc.x, vc.y, vc.z, vc.w);
            o.w = pack4_fp8(vd.x, vd.y, vd.z, vd.w);
            dbt8[((size_t)lt * KSTEPS + g) * 512 + idx] = o;
            part[idx] = ss;
        }
        __syncthreads();
        if (t < 128) {
            int base = (t >> 5) * 128 + (t & 31);
            float s = part[base] + part[base + 32] + part[base + 64] + part[base + 96];
            x2p[((size_t)lt * KSTEPS + g) * 128 + t] = s;
        }
    } else {
        // ---------------- q path ----------------
        const int qt = blockIdx.x - LT;      // 0..31
        const int b  = qt >> 3;
        const int p0 = (qt & 7) * 128;

        #pragma unroll
        for (int pass = 0; pass < 2; ++pass) {
            int idx = pass * 256 + t;          // bits [rg:2][h2:1][kc:1][r:5]
            int r  = idx & 31;
            int kc = (idx >> 5) & 1;
            int h2 = (idx >> 6) & 1;
            int rg = idx >> 7;
            int prow = rg * 32 + r;
            int kb = g * 64 + kc * 32 + h2 * 16;
            const float* src = emb + ((size_t)b * D + kb) * HW + p0 + prow;
            float v[16];
            float ss = 0.f;
            #pragma unroll
            for (int j = 0; j < 16; ++j) {
                v[j] = src[(size_t)j * HW];
                ss = fmaf(v[j], v[j], ss);
            }
            uint4 o;
            o.x = pack4_fp8(-2.f*v[0],  -2.f*v[1],  -2.f*v[2],  -2.f*v[3]);
            o.y = pack4_fp8(-2.f*v[4],  -2.f*v[5],  -2.f*v[6],  -2.f*v[7]);
            o.z = pack4_fp8(-2.f*v[8],  -2.f*v[9],  -2.f*v[10], -2.f*v[11]);
            o.w = pack4_fp8(-2.f*v[12], -2.f*v[13], -2.f*v[14], -2.f*v[15]);
            qbt8[((size_t)qt * KSTEPS + g) * 512 + idx] = o;
            part[idx] = ss;
        }
        __syncthreads();
        if (t < 128) {
            int base = (t >> 5) * 128 + (t & 31);
            float s = part[base] + part[base + 32] + part[base + 64] + part[base + 96];
            q2p[((size_t)qt * KSTEPS + g) * 128 + t] = s;
        }
    }
}

// ---------------------------------------------------------------------------
// 2) MX-fp8 MFMA GEMM — r5 skeleton with HALF the barriers (BK=128):
//    __syncthreads only at even K-steps; B ring = 4x8KB staged 2 steps
//    ahead. Everything else identical to the proven r5 kernel (A direct
//    global->VGPR with one-step register prefetch, per-lane x2 + __shfl,
//    no inline asm / sched fences / setprio).
//    Hazard ledger (barriers at even g; parity-checked both cases):
//      RAW stage->read : stage(gs=g+2) issued at step g, consumed at step
//        g+2; an even barrier lies at g+1 or g+2, strictly between issue
//        and consumption, and its __syncthreads vmcnt(0) drains it.
//      WAR read->stage : ring[r] read at step s is next overwritten at
//        step s+2 (writes ring[(s+2+2-4)&3]... i.e. same slot); an even
//        barrier lies strictly between (at s+1 or s+2), and its lgkmcnt(0)
//        drain covers the readers' ds_reads.
//      A loads: plain VGPR loads, compiler-inserted waitcnt before use.
//      12 % 4 == 0 -> ring phase is tile-invariant; next tile's B(0),B(1)
//      staged at g=10,11 into rings 0,1 matching the prologue layout.
__global__ __launch_bounds__(256, 2) void gemm_topk(const unsigned char* __restrict__ dbt8,
                                                    const unsigned char* __restrict__ qbt8,
                                                    const float* __restrict__ x2p,
                                                    float* __restrict__ partials) {
    __shared__ __align__(16) unsigned char Bsm[4 * 8192];   // 32 KB ring
    __shared__ float red[4][BN][3];                         // 6 KB

    const int tid  = threadIdx.x;
    const int lane = tid & 63;
    const int w    = tid >> 6;           // 0..3
    const int lts  = w >> 1;             // which layout tile of the pair
    const int wr   = w & 1;              // which half of it
    const int h    = lane >> 5;
    const int l31  = lane & 31;

    const int bid   = blockIdx.x;        // 0..511
    const int xcd   = bid & 7;
    const int j     = bid >> 3;
    const int sp    = xcd + 8 * (j >> 5);   // 0..15
    const int qtile = j & 31;
    const int m0    = qtile * BN;

    int b_off[4];
    #pragma unroll
    for (int j4 = 0; j4 < 4; ++j4) b_off[j4] = j4 * 2048 + h * 512 + l31 * 16;

    // A fragment global base (per wave): layout tile 2sp+lts, quarter wr.
    const unsigned char* aT = dbt8 + (size_t)(2 * sp + lts) * KSTEPS * STEPB
                              + wr * 4096 + h * 512 + l31 * 16;

    // B staging (per wave: 2 KB of each 8 KB step-block)
    const unsigned char* bQ = qbt8 + (size_t)qtile * KSTEPS * STEPB + w * 2048 + lane * 16;
    unsigned char* bD = Bsm + w * 2048;   // + ring*8192

    // loads write DIRECTLY into the i32x8 halves (no v_mov assembly)
    auto ldA = [&](i32x8& x0, i32x8& x1, const unsigned char* p) {
        *(int4*)&x0       = *(const int4*)(p);
        *((int4*)&x0 + 1) = *(const int4*)(p + 1024);
        *(int4*)&x1       = *(const int4*)(p + 2048);
        *((int4*)&x1 + 1) = *(const int4*)(p + 3072);
    };
    auto ldB = [&](i32x8& f, const unsigned char* Bb, int off) {
        *(int4*)&f       = *(const int4*)(Bb + off);
        *((int4*)&f + 1) = *(const int4*)(Bb + off + 1024);
    };

    // prologue: stage B(0)->ring0, B(1)->ring1
    gl_lds16(bQ,                bD);
    gl_lds16(bQ + 1024,         bD + 1024);
    gl_lds16(bQ + STEPB,        bD + 8192);
    gl_lds16(bQ + STEPB + 1024, bD + 8192 + 1024);

    float t0[4], t1[4], t2[4];
    #pragma unroll
    for (int j4 = 0; j4 < 4; ++j4) { t0[j4] = INFINITY; t1[j4] = INFINITY; t2[j4] = INFINITY; }

    for (int tile = sp; tile < NT2; tile += NSPLIT) {
        const bool lastTile = (tile + NSPLIT >= NT2);

        // per-lane x2: lane l holds db row n = tile*256 + w*64 + l (pad -> 1e30)
        float sx = 1e30f;
        {
            int n = tile * BM + w * 64 + lane;
            if (n < NDB) {
                const float* p = x2p + (size_t)(n >> 7) * (KSTEPS * 128) + (n & 127);
                sx = 0.f;
                #pragma unroll
                for (int g = 0; g < KSTEPS; ++g) sx += p[g * 128];
            }
        }

        f32x16 acc[2][4];
        #pragma unroll
        for (int i = 0; i < 2; ++i)
            #pragma unroll
            for (int j4 = 0; j4 < 4; ++j4)
                #pragma unroll
                for (int r = 0; r < 16; ++r) acc[i][j4][r] = 0.f;

        i32x8 af0, af1, an0, an1;
        ldA(af0, af1, aT);                 // A(tile,0)

        #pragma unroll 4
        for (int g = 0; g < KSTEPS; ++g) {
            if ((g & 1) == 0) __syncthreads();   // barrier every 2 K-steps

            // stage B(g+2) (wraps to next tile's B(0)/B(1); B is tile-invariant)
            {
                int gs = g + 2;
                unsigned char* dst = bD + ((g + 2) & 3) * 8192;
                if (gs < KSTEPS) {
                    gl_lds16(bQ + gs * STEPB,        dst);
                    gl_lds16(bQ + gs * STEPB + 1024, dst + 1024);
                } else if (!lastTile) {
                    gl_lds16(bQ + (gs - KSTEPS) * STEPB,        dst);
                    gl_lds16(bQ + (gs - KSTEPS) * STEPB + 1024, dst + 1024);
                }
            }

            // A register prefetch for step g+1
            if (g + 1 < KSTEPS) ldA(an0, an1, aT + (g + 1) * STEPB);

            // B fragments for step g from ring[g&3]
            const unsigned char* Bb = Bsm + (g & 3) * 8192;
            i32x8 bf[4];
            #pragma unroll
            for (int j4 = 0; j4 < 4; ++j4) ldB(bf[j4], Bb, b_off[j4]);

            #pragma unroll
            for (int j4 = 0; j4 < 4; ++j4) {
                acc[0][j4] = __builtin_amdgcn_mfma_scale_f32_32x32x64_f8f6f4(
                    af0, bf[j4], acc[0][j4], 0, 0, 0, 0x7f7f7f7f, 0, 0x7f7f7f7f);
                acc[1][j4] = __builtin_amdgcn_mfma_scale_f32_32x32x64_f8f6f4(
                    af1, bf[j4], acc[1][j4], 0, 0, 0, 0x7f7f7f7f, 0, 0x7f7f7f7f);
            }
            af0 = an0; af1 = an1;
        }
        aT += (size_t)2 * NSPLIT * KSTEPS * STEPB;   // next tile's A base

        // epilogue: rows = w*64 + i*32 + rg2*8 + 4h + rr; cols = j4*32 + l31
        #pragma unroll
        for (int i = 0; i < 2; ++i) {
            #pragma unroll
            for (int rg2 = 0; rg2 < 4; ++rg2) {
                #pragma unroll
                for (int rr = 0; rr < 4; ++rr) {
                    float xv = __shfl(sx, i * 32 + rg2 * 8 + 4 * h + rr);
                    #pragma unroll
                    for (int j4 = 0; j4 < 4; ++j4)
                        insert3(t0[j4], t1[j4], t2[j4], acc[i][j4][rg2 * 4 + rr] + xv);
                }
            }
        }
    }

    // merge across row-halves (lane^32; col = l31 preserved)
    #pragma unroll
    for (int j4 = 0; j4 < 4; ++j4) {
        float o0 = __shfl_xor(t0[j4], 32);
        float o1 = __shfl_xor(t1[j4], 32);
        float o2 = __shfl_xor(t2[j4], 32);
        insert3(t0[j4], t1[j4], t2[j4], o0);
        insert3(t0[j4], t1[j4], t2[j4], o1);
        insert3(t0[j4], t1[j4], t2[j4], o2);
    }
    if (h == 0) {
        #pragma unroll
        for (int j4 = 0; j4 < 4; ++j4) {
            int col = j4 * 32 + l31;
            red[w][col][0] = t0[j4];
            red[w][col][1] = t1[j4];
            red[w][col][2] = t2[j4];
        }
    }
    __syncthreads();
    if (tid < BN) {
        float a0 = red[0][tid][0], a1 = red[0][tid][1], a2 = red[0][tid][2];
        #pragma unroll
        for (int ww = 1; ww < 4; ++ww) {
            insert3(a0, a1, a2, red[ww][tid][0]);
            insert3(a0, a1, a2, red[ww][tid][1]);
            insert3(a0, a1, a2, red[ww][tid][2]);
        }
        float* dst = partials + ((size_t)(m0 + tid) * NSPLIT + sp) * 3;
        dst[0] = a0; dst[1] = a1; dst[2] = a2;
    }
}

// ---------------------------------------------------------------------------
// 3) merge partials, reduce q2 partials, sqrt, mean
__global__ __launch_bounds__(256) void merge_ood(const float* __restrict__ partials,
                                                 const float* __restrict__ q2p,
                                                 float* __restrict__ ood) {
    int m = blockIdx.x * 256 + threadIdx.x;
    if (m >= M) return;
    const float* pp = partials + (size_t)m * NSPLIT * 3;
    float a0 = INFINITY, a1 = INFINITY, a2 = INFINITY;
    #pragma unroll
    for (int j = 0; j < NSPLIT * 3; ++j) insert3(a0, a1, a2, pp[j]);
    const float* qp = q2p + (size_t)(m >> 7) * KSTEPS * 128 + (m & 127);
    float q = 0.f;
    #pragma unroll
    for (int g = 0; g < KSTEPS; ++g) q += qp[g * 128];
    float d0 = sqrtf(fmaxf(q + a0, 1e-12f));
    float d1 = sqrtf(fmaxf(q + a1, 1e-12f));
    float d2 = sqrtf(fmaxf(q + a2, 1e-12f));
    ood[m] = (d0 + d1 + d2) * (1.f / 3.f);
}

// ---------------------------------------------------------------------------
// 4) half-pixel bilinear 32x32 -> 512x512
__global__ __launch_bounds__(256) void upsample(const float* __restrict__ ood,
                                                float* __restrict__ out) {
    int idx = blockIdx.x * 256 + threadIdx.x;
    int ox = idx & (OUTW - 1);
    int oy = (idx >> 9) & (OUTH - 1);
    int bb = idx >> 18;
    float sx = (ox + 0.5f) * (32.f / OUTW) - 0.5f;
    float sy = (oy + 0.5f) * (32.f / OUTH) - 0.5f;
    float fx = floorf(sx), fy = floorf(sy);
    float wx = sx - fx, wy = sy - fy;
    int x0 = max(0, min(31, (int)fx));
    int x1 = max(0, min(31, (int)fx + 1));
    int y0 = max(0, min(31, (int)fy));
    int y1 = max(0, min(31, (int)fy + 1));
    const float* src = ood + bb * 1024;
    float v00 = src[y0 * 32 + x0];
    float v01 = src[y0 * 32 + x1];
    float v10 = src[y1 * 32 + x0];
    float v11 = src[y1 * 32 + x1];
    float top = v00 + wx * (v01 - v00);
    float bot = v10 + wx * (v11 - v10);
    out[idx] = top + wy * (bot - top);
}

// ---------------------------------------------------------------------------
extern "C" void kernel_launch(void* const* d_in, const int* in_sizes, int n_in,
                              void* d_out, int out_size, void* d_ws, size_t ws_size,
                              hipStream_t stream) {
    const float* emb = (const float*)d_in[0];
    const float* db  = (const float*)d_in[1];
    float* out = (float*)d_out;

    // workspace layout (bytes), total ~20.7 MB
    char* ws = (char*)d_ws;
    unsigned char* dbt8 = (unsigned char*)ws;                    // 158*12*8192 = 15,532,032
    unsigned char* qbt8 = (unsigned char*)(ws + 15532032);       // 32*12*8192  =  3,145,728
    float* x2p      = (float*)(ws + 18677760);                   // 158*12*128*4 = 970,752
    float* q2p      = (float*)(ws + 19648512);                   // 32*12*128*4 = 196,608
    float* ood      = (float*)(ws + 19845120);                   // 16,384
    float* partials = (float*)(ws + 19861504);                   // 4096*16*3*4 = 786,432

    convert_all<<<dim3(LT + 32, KSTEPS), 256, 0, stream>>>(db, emb, (uint4*)dbt8,
                                                           (uint4*)qbt8, x2p, q2p);
    gemm_topk<<<NSPLIT * 32, 256, 0, stream>>>(dbt8, qbt8, x2p, partials);
    merge_ood<<<(M + 255) / 256, 256, 0, stream>>>(partials, q2p, ood);
    upsample<<<(B * OUTH * OUTW) / 256, 256, 0, stream>>>(ood, out);
}

// Round 9
// 178.328 us; speedup vs baseline: 1.7043x; 1.7043x over previous
//
#include <hip/hip_runtime.h>
#include <hip/hip_bf16.h>
#include <math.h>

// Problem constants
constexpr int B    = 4;
constexpr int D    = 768;
constexpr int HW   = 1024;
constexpr int M    = B * HW;        // 4096 queries
constexpr int NDB  = 20000;
constexpr int LT   = 158;           // 128-row layout tiles (20224 rows padded)
constexpr int OUTH = 512;
constexpr int OUTW = 512;

constexpr int BM     = 256;         // db rows per gemm tile (2 layout tiles)
constexpr int BN     = 128;         // queries per tile
constexpr int KSTEPS = D / 64;      // 12 64-K steps
constexpr int NSPLIT = 16;
constexpr int NT2    = 79;          // 256-row gemm tiles
constexpr int STEPB  = 128 * 64;    // 8192 B per 64-K step-block (one layout tile)

typedef int   i32x8  __attribute__((ext_vector_type(8)));
typedef float f32x16 __attribute__((ext_vector_type(16)));

__device__ __forceinline__ void insert3(float& t0, float& t1, float& t2, float d) {
    float a0 = fminf(d, t0);
    float b0 = fmaxf(d, t0);
    float a1 = fminf(b0, t1);
    float b1 = fmaxf(b0, t1);
    t0 = a0; t1 = a1;
    t2 = fminf(b1, t2);
}

__device__ __forceinline__ unsigned int pack4_fp8(float a, float b, float c, float d) {
    int v = __builtin_amdgcn_cvt_pk_fp8_f32(a, b, 0, false);
    v = __builtin_amdgcn_cvt_pk_fp8_f32(c, d, v, true);
    return (unsigned int)v;
}

__device__ __forceinline__ void gl_lds16(const unsigned char* g, unsigned char* l) {
    __builtin_amdgcn_global_load_lds(
        (const __attribute__((address_space(1))) void*)g,
        (__attribute__((address_space(3))) void*)l, 16, 0, 0);
}

// ---------------------------------------------------------------------------
// 1) Fused converts (one launch, block-uniform branch):
//    blockIdx.x <  LT : db [20000][768] fp32 -> fp8 tiled
//                       [158][12][rg 4][h2 2][kc 2][r 32][16B], + x2 partials
//    blockIdx.x >= LT : emb [4][768][1024] -> fp8 (-2*q) tiled
//                       [32][12][rg][h2][kc][r][16B], + q2 partials
__global__ __launch_bounds__(256) void convert_all(const float* __restrict__ db,
                                                   const float* __restrict__ emb,
                                                   uint4* __restrict__ dbt8,
                                                   uint4* __restrict__ qbt8,
                                                   float* __restrict__ x2p,
                                                   float* __restrict__ q2p) {
    __shared__ float panel[128][68];
    __shared__ float part[512];
    const int g = blockIdx.y;
    const int t = threadIdx.x;

    if (blockIdx.x < LT) {
        // ---------------- db path ----------------
        const int lt = blockIdx.x;
        const int n0 = lt * 128;

        #pragma unroll
        for (int pass = 0; pass < 8; ++pass) {
            int idx = pass * 256 + t;            // 0..2047
            int row = idx >> 4, c4 = idx & 15;
            int n = n0 + row;
            float4 v = make_float4(0.f, 0.f, 0.f, 0.f);
            if (n < NDB) v = *(const float4*)(db + (size_t)n * D + g * 64 + c4 * 4);
            *(float4*)&panel[row][c4 * 4] = v;
        }
        __syncthreads();
        #pragma unroll
        for (int pass = 0; pass < 2; ++pass) {
            int idx = pass * 256 + t;            // bits [rg:2][h2:1][kc:1][r:5]
            int r  = idx & 31;
            int kc = (idx >> 5) & 1;
            int h2 = (idx >> 6) & 1;
            int rg = idx >> 7;
            int row  = rg * 32 + r;
            int kloc = kc * 32 + h2 * 16;
            float4 va = *(const float4*)&panel[row][kloc + 0];
            float4 vb = *(const float4*)&panel[row][kloc + 4];
            float4 vc = *(const float4*)&panel[row][kloc + 8];
            float4 vd = *(const float4*)&panel[row][kloc + 12];
            float ss = va.x*va.x + va.y*va.y + va.z*va.z + va.w*va.w
                     + vb.x*vb.x + vb.y*vb.y + vb.z*vb.z + vb.w*vb.w
                     + vc.x*vc.x + vc.y*vc.y + vc.z*vc.z + vc.w*vc.w
                     + vd.x*vd.x + vd.y*vd.y + vd.z*vd.z + vd.w*vd.w;
            uint4 o;
            o.x = pack4_fp8(va.x, va.y, va.z, va.w);
            o.y = pack4_fp8(vb.x, vb.y, vb.z, vb.w);
            o.z = pack4_fp8(vc.x, vc.y, vc.z, vc.w);
            o.w = pack4_fp8(vd.x, vd.y, vd.z, vd.w);
            dbt8[((size_t)lt * KSTEPS + g) * 512 + idx] = o;
            part[idx] = ss;
        }
        __syncthreads();
        if (t < 128) {
            int base = (t >> 5) * 128 + (t & 31);
            float s = part[base] + part[base + 32] + part[base + 64] + part[base + 96];
            x2p[((size_t)lt * KSTEPS + g) * 128 + t] = s;
        }
    } else {
        // ---------------- q path ----------------
        const int qt = blockIdx.x - LT;      // 0..31
        const int b  = qt >> 3;
        const int p0 = (qt & 7) * 128;

        #pragma unroll
        for (int pass = 0; pass < 2; ++pass) {
            int idx = pass * 256 + t;          // bits [rg:2][h2:1][kc:1][r:5]
            int r  = idx & 31;
            int kc = (idx >> 5) & 1;
            int h2 = (idx >> 6) & 1;
            int rg = idx >> 7;
            int prow = rg * 32 + r;
            int kb = g * 64 + kc * 32 + h2 * 16;
            const float* src = emb + ((size_t)b * D + kb) * HW + p0 + prow;
            float v[16];
            float ss = 0.f;
            #pragma unroll
            for (int j = 0; j < 16; ++j) {
                v[j] = src[(size_t)j * HW];
                ss = fmaf(v[j], v[j], ss);
            }
            uint4 o;
            o.x = pack4_fp8(-2.f*v[0],  -2.f*v[1],  -2.f*v[2],  -2.f*v[3]);
            o.y = pack4_fp8(-2.f*v[4],  -2.f*v[5],  -2.f*v[6],  -2.f*v[7]);
            o.z = pack4_fp8(-2.f*v[8],  -2.f*v[9],  -2.f*v[10], -2.f*v[11]);
            o.w = pack4_fp8(-2.f*v[12], -2.f*v[13], -2.f*v[14], -2.f*v[15]);
            qbt8[((size_t)qt * KSTEPS + g) * 512 + idx] = o;
            part[idx] = ss;
        }
        __syncthreads();
        if (t < 128) {
            int base = (t >> 5) * 128 + (t & 31);
            float s = part[base] + part[base + 32] + part[base + 64] + part[base + 96];
            q2p[((size_t)qt * KSTEPS + g) * 128 + t] = s;
        }
    }
}

// ---------------------------------------------------------------------------
// 2) MX-fp8 MFMA GEMM — round-5 skeleton + BK=128 barrier-halving, with
//    round-5's PROVEN codegen (int4 loads + vector-literal construction;
//    NO type-punned partial writes — round-8's punning caused 462 MB of
//    scratch spills). __syncthreads only at even K-steps; B ring = 4x8KB
//    staged 2 steps ahead. A direct global->VGPR with one-step register
//    prefetch; per-lane x2 + __shfl; no inline asm / fences / setprio.
//    Hazard ledger (barriers at even g; both parities checked):
//      RAW stage->read : stage(s) issued at step s-2; even barrier at s-1
//        (s odd) or s (s even, before the ds_reads) lies between; its
//        vmcnt(0) drain covers it.
//      WAR read->stage : ring slot read at step s is overwritten by the
//        stage issued at step s+2; even barrier at s+1 or s+2 (before the
//        stage) lies between; its lgkmcnt(0) drain covers the readers.
//      A loads: plain VGPR loads, compiler-inserted waitcnt before use.
//      12 % 4 == 0 -> ring phase tile-invariant; wrap stages at g=10,11
//      fill rings 0,1 = next tile's B(0),B(1) (B is tile-invariant).
__global__ __launch_bounds__(256, 2) void gemm_topk(const unsigned char* __restrict__ dbt8,
                                                    const unsigned char* __restrict__ qbt8,
                                                    const float* __restrict__ x2p,
                                                    float* __restrict__ partials) {
    __shared__ __align__(16) unsigned char Bsm[4 * 8192];   // 32 KB ring
    __shared__ float red[4][BN][3];                         // 6 KB

    const int tid  = threadIdx.x;
    const int lane = tid & 63;
    const int w    = tid >> 6;           // 0..3
    const int lts  = w >> 1;             // which layout tile of the pair
    const int wr   = w & 1;              // which half of it
    const int h    = lane >> 5;
    const int l31  = lane & 31;

    const int bid   = blockIdx.x;        // 0..511
    const int xcd   = bid & 7;
    const int j     = bid >> 3;
    const int sp    = xcd + 8 * (j >> 5);   // 0..15
    const int qtile = j & 31;
    const int m0    = qtile * BN;

    int b_off[4];
    #pragma unroll
    for (int j4 = 0; j4 < 4; ++j4) b_off[j4] = j4 * 2048 + h * 512 + l31 * 16;

    // A fragment global base (per wave): layout tile 2sp+lts, quarter wr.
    const unsigned char* aT = dbt8 + (size_t)(2 * sp + lts) * KSTEPS * STEPB
                              + wr * 4096 + h * 512 + l31 * 16;

    // B staging (per wave: 2 KB of each 8 KB step-block)
    const unsigned char* bQ = qbt8 + (size_t)qtile * KSTEPS * STEPB + w * 2048 + lane * 16;
    unsigned char* bD = Bsm + w * 2048;   // + ring*8192

    auto ldA = [&](i32x8& x0, i32x8& x1, const unsigned char* p) {
        int4 a = *(const int4*)(p);
        int4 b = *(const int4*)(p + 1024);
        int4 c = *(const int4*)(p + 2048);
        int4 d = *(const int4*)(p + 3072);
        x0 = (i32x8){a.x, a.y, a.z, a.w, b.x, b.y, b.z, b.w};
        x1 = (i32x8){c.x, c.y, c.z, c.w, d.x, d.y, d.z, d.w};
    };
    auto ldB = [&](i32x8& f, const unsigned char* Bb, int off) {
        int4 lo = *(const int4*)(Bb + off);
        int4 hi = *(const int4*)(Bb + off + 1024);
        f = (i32x8){lo.x, lo.y, lo.z, lo.w, hi.x, hi.y, hi.z, hi.w};
    };

    // prologue: stage B(0)->ring0, B(1)->ring1
    gl_lds16(bQ,                bD);
    gl_lds16(bQ + 1024,         bD + 1024);
    gl_lds16(bQ + STEPB,        bD + 8192);
    gl_lds16(bQ + STEPB + 1024, bD + 8192 + 1024);

    float t0[4], t1[4], t2[4];
    #pragma unroll
    for (int j4 = 0; j4 < 4; ++j4) { t0[j4] = INFINITY; t1[j4] = INFINITY; t2[j4] = INFINITY; }

    for (int tile = sp; tile < NT2; tile += NSPLIT) {
        const bool lastTile = (tile + NSPLIT >= NT2);

        // per-lane x2: lane l holds db row n = tile*256 + w*64 + l (pad -> 1e30)
        float sx = 1e30f;
        {
            int n = tile * BM + w * 64 + lane;
            if (n < NDB) {
                const float* p = x2p + (size_t)(n >> 7) * (KSTEPS * 128) + (n & 127);
                sx = 0.f;
                #pragma unroll
                for (int g = 0; g < KSTEPS; ++g) sx += p[g * 128];
            }
        }

        f32x16 acc[2][4];
        #pragma unroll
        for (int i = 0; i < 2; ++i)
            #pragma unroll
            for (int j4 = 0; j4 < 4; ++j4)
                #pragma unroll
                for (int r = 0; r < 16; ++r) acc[i][j4][r] = 0.f;

        i32x8 af0, af1, an0, an1;
        ldA(af0, af1, aT);                 // A(tile,0)

        #pragma unroll 2
        for (int g = 0; g < KSTEPS; ++g) {
            if ((g & 1) == 0) __syncthreads();   // barrier every 2 K-steps

            // stage B(g+2) into ring[(g+2)&3] (wraps to next tile's B(0)/B(1))
            {
                int gs = g + 2;
                unsigned char* dst = bD + ((g + 2) & 3) * 8192;
                if (gs < KSTEPS) {
                    gl_lds16(bQ + gs * STEPB,        dst);
                    gl_lds16(bQ + gs * STEPB + 1024, dst + 1024);
                } else if (!lastTile) {
                    gl_lds16(bQ + (gs - KSTEPS) * STEPB,        dst);
                    gl_lds16(bQ + (gs - KSTEPS) * STEPB + 1024, dst + 1024);
                }
            }

            // A register prefetch for step g+1
            if (g + 1 < KSTEPS) ldA(an0, an1, aT + (g + 1) * STEPB);

            // B fragments for step g from ring[g&3]
            const unsigned char* Bb = Bsm + (g & 3) * 8192;
            i32x8 bf[4];
            #pragma unroll
            for (int j4 = 0; j4 < 4; ++j4) ldB(bf[j4], Bb, b_off[j4]);

            #pragma unroll
            for (int j4 = 0; j4 < 4; ++j4) {
                acc[0][j4] = __builtin_amdgcn_mfma_scale_f32_32x32x64_f8f6f4(
                    af0, bf[j4], acc[0][j4], 0, 0, 0, 0x7f7f7f7f, 0, 0x7f7f7f7f);
                acc[1][j4] = __builtin_amdgcn_mfma_scale_f32_32x32x64_f8f6f4(
                    af1, bf[j4], acc[1][j4], 0, 0, 0, 0x7f7f7f7f, 0, 0x7f7f7f7f);
            }
            af0 = an0; af1 = an1;
        }
        aT += (size_t)2 * NSPLIT * KSTEPS * STEPB;   // next tile's A base

        // epilogue: rows = w*64 + i*32 + rg2*8 + 4h + rr; cols = j4*32 + l31
        #pragma unroll
        for (int i = 0; i < 2; ++i) {
            #pragma unroll
            for (int rg2 = 0; rg2 < 4; ++rg2) {
                #pragma unroll
                for (int rr = 0; rr < 4; ++rr) {
                    float xv = __shfl(sx, i * 32 + rg2 * 8 + 4 * h + rr);
                    #pragma unroll
                    for (int j4 = 0; j4 < 4; ++j4)
                        insert3(t0[j4], t1[j4], t2[j4], acc[i][j4][rg2 * 4 + rr] + xv);
                }
            }
        }
    }

    // merge across row-halves (lane^32; col = l31 preserved)
    #pragma unroll
    for (int j4 = 0; j4 < 4; ++j4) {
        float o0 = __shfl_xor(t0[j4], 32);
        float o1 = __shfl_xor(t1[j4], 32);
        float o2 = __shfl_xor(t2[j4], 32);
        insert3(t0[j4], t1[j4], t2[j4], o0);
        insert3(t0[j4], t1[j4], t2[j4], o1);
        insert3(t0[j4], t1[j4], t2[j4], o2);
    }
    if (h == 0) {
        #pragma unroll
        for (int j4 = 0; j4 < 4; ++j4) {
            int col = j4 * 32 + l31;
            red[w][col][0] = t0[j4];
            red[w][col][1] = t1[j4];
            red[w][col][2] = t2[j4];
        }
    }
    __syncthreads();
    if (tid < BN) {
        float a0 = red[0][tid][0], a1 = red[0][tid][1], a2 = red[0][tid][2];
        #pragma unroll
        for (int ww = 1; ww < 4; ++ww) {
            insert3(a0, a1, a2, red[ww][tid][0]);
            insert3(a0, a1, a2, red[ww][tid][1]);
            insert3(a0, a1, a2, red[ww][tid][2]);
        }
        float* dst = partials + ((size_t)(m0 + tid) * NSPLIT + sp) * 3;
        dst[0] = a0; dst[1] = a1; dst[2] = a2;
    }
}

// ---------------------------------------------------------------------------
// 3) merge partials, reduce q2 partials, sqrt, mean
__global__ __launch_bounds__(256) void merge_ood(const float* __restrict__ partials,
                                                 const float* __restrict__ q2p,
                                                 float* __restrict__ ood) {
    int m = blockIdx.x * 256 + threadIdx.x;
    if (m >= M) return;
    const float* pp = partials + (size_t)m * NSPLIT * 3;
    float a0 = INFINITY, a1 = INFINITY, a2 = INFINITY;
    #pragma unroll
    for (int j = 0; j < NSPLIT * 3; ++j) insert3(a0, a1, a2, pp[j]);
    const float* qp = q2p + (size_t)(m >> 7) * KSTEPS * 128 + (m & 127);
    float q = 0.f;
    #pragma unroll
    for (int g = 0; g < KSTEPS; ++g) q += qp[g * 128];
    float d0 = sqrtf(fmaxf(q + a0, 1e-12f));
    float d1 = sqrtf(fmaxf(q + a1, 1e-12f));
    float d2 = sqrtf(fmaxf(q + a2, 1e-12f));
    ood[m] = (d0 + d1 + d2) * (1.f / 3.f);
}

// ---------------------------------------------------------------------------
// 4) half-pixel bilinear 32x32 -> 512x512
__global__ __launch_bounds__(256) void upsample(const float* __restrict__ ood,
                                                float* __restrict__ out) {
    int idx = blockIdx.x * 256 + threadIdx.x;
    int ox = idx & (OUTW - 1);
    int oy = (idx >> 9) & (OUTH - 1);
    int bb = idx >> 18;
    float sx = (ox + 0.5f) * (32.f / OUTW) - 0.5f;
    float sy = (oy + 0.5f) * (32.f / OUTH) - 0.5f;
    float fx = floorf(sx), fy = floorf(sy);
    float wx = sx - fx, wy = sy - fy;
    int x0 = max(0, min(31, (int)fx));
    int x1 = max(0, min(31, (int)fx + 1));
    int y0 = max(0, min(31, (int)fy));
    int y1 = max(0, min(31, (int)fy + 1));
    const float* src = ood + bb * 1024;
    float v00 = src[y0 * 32 + x0];
    float v01 = src[y0 * 32 + x1];
    float v10 = src[y1 * 32 + x0];
    float v11 = src[y1 * 32 + x1];
    float top = v00 + wx * (v01 - v00);
    float bot = v10 + wx * (v11 - v10);
    out[idx] = top + wy * (bot - top);
}

// ---------------------------------------------------------------------------
extern "C" void kernel_launch(void* const* d_in, const int* in_sizes, int n_in,
                              void* d_out, int out_size, void* d_ws, size_t ws_size,
                              hipStream_t stream) {
    const float* emb = (const float*)d_in[0];
    const float* db  = (const float*)d_in[1];
    float* out = (float*)d_out;

    // workspace layout (bytes), total ~20.7 MB
    char* ws = (char*)d_ws;
    unsigned char* dbt8 = (unsigned char*)ws;                    // 158*12*8192 = 15,532,032
    unsigned char* qbt8 = (unsigned char*)(ws + 15532032);       // 32*12*8192  =  3,145,728
    float* x2p      = (float*)(ws + 18677760);                   // 158*12*128*4 = 970,752
    float* q2p      = (float*)(ws + 19648512);                   // 32*12*128*4 = 196,608
    float* ood      = (float*)(ws + 19845120);                   // 16,384
    float* partials = (float*)(ws + 19861504);                   // 4096*16*3*4 = 786,432

    convert_all<<<dim3(LT + 32, KSTEPS), 256, 0, stream>>>(db, emb, (uint4*)dbt8,
                                                           (uint4*)qbt8, x2p, q2p);
    gemm_topk<<<NSPLIT * 32, 256, 0, stream>>>(dbt8, qbt8, x2p, partials);
    merge_ood<<<(M + 255) / 256, 256, 0, stream>>>(partials, q2p, ood);
    upsample<<<(B * OUTH * OUTW) / 256, 256, 0, stream>>>(ood, out);
}